// Round 9
// baseline (257.894 us; speedup 1.0000x reference)
//
#include <hip/hip_runtime.h>

typedef float  f32x4  __attribute__((ext_vector_type(4)));
typedef __bf16 bf16x8 __attribute__((ext_vector_type(8)));

#define CC 384
#define AS1 __attribute__((address_space(1)))
#define AS3 __attribute__((address_space(3)))

__device__ __forceinline__ unsigned short f2bf(float f) {
  union { float f; unsigned int u; } x; x.f = f;
  unsigned int u = x.u;
  return (unsigned short)((u + 0x7fffu + ((u >> 16) & 1u)) >> 16);
}

__device__ __forceinline__ f32x4 mfma16(bf16x8 a, bf16x8 b, f32x4 c) {
  return __builtin_amdgcn_mfma_f32_16x16x32_bf16(a, b, c, 0, 0, 0);
}

// ---------------- kernel 0: repack W into B-fragment layout ----------------
// dst: [ks(0..11)][nt(0..11)][lane(0..63)][j(0..7)] bf16
// element (k, n): ks=k>>5, lane=((k>>3)&3)*16 + (n&15), j=k&7, nt=n>>4
__global__ void repack_w(const float* __restrict__ Wq, const float* __restrict__ Wk,
                         const float* __restrict__ Wv, unsigned short* __restrict__ wf) {
  int e = blockIdx.x * 512 + threadIdx.x;      // 73728 total, exact
  int k = e / 192;
  int n = e - k * 192;
  const float* W = (n < 64) ? Wq : (n < 128) ? Wk : Wv;
  float val = W[k * 64 + (n & 63)];
  int kk = k >> 5;
  int lane = (((k >> 3) & 3) << 4) | (n & 15);
  int j = k & 7;
  int nt = n >> 4;
  wf[(size_t)(((kk * 12 + nt) << 6) + lane) * 8 + j] = f2bf(val);
}

// ---------------- fused kernel: projection + column-softmax attention ----------------
// ONE block per batch, 1024 threads / 16 waves, LDS 48KB, VGPR<=64:
//   => 2 INDEPENDENT blocks co-resident per CU (8 waves/SIMD), single grid round.
//   Block-level overlap is the point: one block's barrier drains hide under the
//   sibling block's compute (R8 measured: 1 block/CU @119.8KB LDS left every pipe
//   <25% busy despite 42% occupancy — intra-block waves are barrier-lockstepped).
//  - projection: wave w owns m-tile w (16 rows), acc[12] = 48 regs.
//  - attention: wave pair {u, u+8}: S-phase split by column-half, PV by head-half.
//  - k/v live in GLOBAL (L2-hot, 64KB/block working set); only Sx+stats in LDS.
__global__ __launch_bounds__(1024, 8) void fused(const float* __restrict__ x,
                                                 const unsigned short* __restrict__ wf,
                                                 unsigned short* __restrict__ kg,
                                                 unsigned short* __restrict__ vg,
                                                 float* __restrict__ out) {
  // LDS layout (49,152 B):
  //  [0, 36864)        Sx[256][72] bf16  (projection W-stage dbuf overlay / q-scratch / exp)
  //  [36864, 49152)    pm/ps/gg [16][64] f32 each  (dead during projection => wst overlay OK)
  __shared__ __attribute__((aligned(16))) unsigned char smem[49152];
  unsigned short (*Sx)[72] = (unsigned short(*)[72])smem;
  float* pm = (float*)(smem + 36864);
  float* ps = pm + 1024;
  float* gg = ps + 1024;
  unsigned short* wst = (unsigned short*)smem;   // 2 x 12288 shorts (24,576 B each)

  const int tid = threadIdx.x;
  const int w = tid >> 6, lane = tid & 63;
  const int l15 = lane & 15, lhi = lane >> 4;
  const int b = blockIdx.x;
  const int u = w & 7, chalf = w >> 3;
  const int mts[2] = {u, 15 - u};

  // ================= projection: 6 phases of K=64, 2-buffer LDS W-stage =================
  const float* xr = x + ((size_t)b * 256 + w * 16 + l15) * CC + lhi * 8;

  f32x4 zero = {0.f, 0.f, 0.f, 0.f};
  f32x4 acc[12];
#pragma unroll
  for (int nt = 0; nt < 12; ++nt) acc[nt] = zero;

#define WSTAGE(kp_, b_) do {                                                                  \
    const unsigned short* s_ = wf + (size_t)(kp_) * 12288 + tid * 8;                          \
    unsigned short* d_ = wst + (b_) * 12288 + tid * 8;                                        \
    __builtin_amdgcn_global_load_lds((const AS1 void*)(s_), (AS3 void*)(d_), 16, 0, 0);       \
    if (tid < 512)                                                                            \
      __builtin_amdgcn_global_load_lds((const AS1 void*)(s_ + 8192), (AS3 void*)(d_ + 8192),  \
                                       16, 0, 0);                                             \
  } while (0)
#define XLOAD(kp_, a_) do {                                                                   \
    const int o_ = (kp_) * 64;                                                                \
    a_[0][0] = *(const f32x4*)(xr + o_);      a_[0][1] = *(const f32x4*)(xr + o_ + 4);        \
    a_[1][0] = *(const f32x4*)(xr + o_ + 32); a_[1][1] = *(const f32x4*)(xr + o_ + 36);       \
  } while (0)

  WSTAGE(0, 0);
  f32x4 aC[2][2];
  XLOAD(0, aC);

  for (int kp = 0; kp < 6; ++kp) {
    __syncthreads();  // buf[kp&1] staged; prev-buf readers done
    f32x4 aN[2][2];
#pragma unroll
    for (int k2 = 0; k2 < 2; ++k2) { aN[k2][0] = zero; aN[k2][1] = zero; }
    if (kp < 5) {
      XLOAD(kp + 1, aN);
      WSTAGE(kp + 1, (kp + 1) & 1);
    }
#pragma unroll
    for (int k2 = 0; k2 < 2; ++k2) {
      bf16x8 af;
#pragma unroll
      for (int j = 0; j < 4; ++j) { af[j] = (__bf16)aC[k2][0][j]; af[4 + j] = (__bf16)aC[k2][1][j]; }
      const bf16x8* bp = (const bf16x8*)(wst + (kp & 1) * 12288 + k2 * 6144) + lane;
#pragma unroll
      for (int nt = 0; nt < 12; ++nt) acc[nt] = mfma16(af, bp[nt * 64], acc[nt]);
    }
#pragma unroll
    for (int k2 = 0; k2 < 2; ++k2) { aC[k2][0] = aN[k2][0]; aC[k2][1] = aN[k2][1]; }
  }
#undef WSTAGE
#undef XLOAD
  __syncthreads();  // all W-stage LDS reads done; Sx/stats regions free

  // epilogue: q (scaled) -> Sx LDS, k -> kg global [b][t][h], v -> vg global [b][h][t]
  const float qs = 0.05103103630798288f;  // 384^-0.5
  {
    const int rb = w * 16 + lhi * 4;
#pragma unroll
    for (int nt = 0; nt < 4; ++nt) {
      const int h = nt * 16 + l15;
#pragma unroll
      for (int r = 0; r < 4; ++r) Sx[rb + r][h] = f2bf(acc[nt][r] * qs);
    }
#pragma unroll
    for (int nt = 4; nt < 8; ++nt) {
      const int h = (nt - 4) * 16 + l15;
#pragma unroll
      for (int r = 0; r < 4; ++r)
        kg[((size_t)b * 256 + rb + r) * 64 + h] = f2bf(acc[nt][r]);
    }
#pragma unroll
    for (int nt = 8; nt < 12; ++nt) {
      const int h = (nt - 8) * 16 + l15;
      unsigned long long pk =
          (unsigned long long)f2bf(acc[nt][0]) |
          ((unsigned long long)f2bf(acc[nt][1]) << 16) |
          ((unsigned long long)f2bf(acc[nt][2]) << 32) |
          ((unsigned long long)f2bf(acc[nt][3]) << 48);
      *(unsigned long long*)(vg + ((size_t)b * 64 + h) * 256 + rb) = pk;
    }
  }
  __syncthreads();  // q in LDS; k/v global writes drained (vmcnt0) -> same-XCD L2 coherent

  bf16x8 qf[2][2];
#pragma unroll
  for (int i = 0; i < 2; ++i)
#pragma unroll
    for (int kk = 0; kk < 2; ++kk)
      qf[i][kk] = *(const bf16x8*)&Sx[mts[i] * 16 + l15][kk * 32 + lhi * 8];
  __syncthreads();  // B0: qf loaded before any wave overwrites Sx

  // ================= attention =================
  f32x4 oacc[2][2];   // [tile][nh-half]; this wave owns head cols chalf*32 .. +31
#pragma unroll
  for (int i = 0; i < 2; ++i)
#pragma unroll
    for (int nh2 = 0; nh2 < 2; ++nh2) oacc[i][nh2] = zero;

  const size_t kbase = (size_t)b * 256 * 64;
  const size_t vbase = (size_t)b * 64 * 256;

  for (int p = 0; p < 4; ++p) {
    const int p4 = 4 * p;
    const bool any = (mts[1] >= p4);
    // ---- S compute (this wave's column-half) + tile-column stats + exp write ----
    if (any) {
      bf16x8 kf[2][2];
#pragma unroll
      for (int c2 = 0; c2 < 2; ++c2) {
        const int c = chalf * 2 + c2;
#pragma unroll
        for (int kk = 0; kk < 2; ++kk)
          kf[c2][kk] = *(const bf16x8*)(kg + kbase + (size_t)(p * 64 + c * 16 + l15) * 64 + kk * 32 + lhi * 8);
      }
#pragma unroll
      for (int i = 0; i < 2; ++i) {
        const int mt = mts[i];
        if (mt < p4) continue;
        const int cmax = mt - p4;
        const int rowb = mt * 16 + lhi * 4;
#pragma unroll
        for (int c2 = 0; c2 < 2; ++c2) {
          const int c = chalf * 2 + c2;
          const int cs = c * 16 + l15;
          if (c <= cmax) {
            f32x4 s = zero;
            s = mfma16(qf[i][0], kf[c2][0], s);
            s = mfma16(qf[i][1], kf[c2][1], s);
            const int cg = p * 64 + cs;
            const bool v0 = (rowb + 0) >= cg, v1 = (rowb + 1) >= cg;
            const bool v2 = (rowb + 2) >= cg, v3 = (rowb + 3) >= cg;
            float m = -1e30f;
            m = fmaxf(m, v0 ? s[0] : -1e30f);
            m = fmaxf(m, v1 ? s[1] : -1e30f);
            m = fmaxf(m, v2 ? s[2] : -1e30f);
            m = fmaxf(m, v3 ? s[3] : -1e30f);
            m = fmaxf(m, __shfl_xor(m, 16));
            m = fmaxf(m, __shfl_xor(m, 32));
            const float e0 = v0 ? __expf(s[0] - m) : 0.f;
            const float e1 = v1 ? __expf(s[1] - m) : 0.f;
            const float e2 = v2 ? __expf(s[2] - m) : 0.f;
            const float e3 = v3 ? __expf(s[3] - m) : 0.f;
            float t = e0 + e1 + e2 + e3;
            t += __shfl_xor(t, 16);
            t += __shfl_xor(t, 32);
            Sx[rowb + 0][cs] = f2bf(e0);
            Sx[rowb + 1][cs] = f2bf(e1);
            Sx[rowb + 2][cs] = f2bf(e2);
            Sx[rowb + 3][cs] = f2bf(e3);
            if (lhi == 0) { pm[mt * 64 + cs] = m; ps[mt * 64 + cs] = t; }
          } else {
            if (lhi == 0) { pm[mt * 64 + cs] = -1e30f; ps[mt * 64 + cs] = 0.f; }
          }
        }
      }
    }
    __syncthreads();  // B1: pm/ps/Sx stripe complete
    // ---- per-column reduce (redundant across waves; wave w writes gg row p4+w) ----
    {
      float M = -1e30f;
      for (int mt = p4; mt < 16; ++mt) M = fmaxf(M, pm[mt * 64 + lane]);
      float L = 0.f;
      for (int mt = p4; mt < 16; ++mt) L += ps[mt * 64 + lane] * __expf(pm[mt * 64 + lane] - M);
      const float rv = 1.0f / L;
      const int mtw = p4 + w;
      if (mtw < 16) gg[mtw * 64 + lane] = __expf(pm[mtw * 64 + lane] - M) * rv;
    }
    __syncthreads();  // B2: gg ready
    // ---- W = Sx * gg, PV accumulate (this wave's head-half) ----
    if (any) {
      bf16x8 vf[2][2];
#pragma unroll
      for (int nh2 = 0; nh2 < 2; ++nh2)
#pragma unroll
        for (int kk = 0; kk < 2; ++kk)
          vf[nh2][kk] = *(const bf16x8*)(vg + vbase + (size_t)((chalf * 2 + nh2) * 16 + l15) * 256 + p * 64 + kk * 32 + lhi * 8);
#pragma unroll
      for (int i = 0; i < 2; ++i) {
        const int mt = mts[i];
        if (mt < p4) continue;
        const int grow = mt * 16 + l15;
        const int dmax = mt - p4;
#pragma unroll
        for (int kk = 0; kk < 2; ++kk) {
          if (kk == 1 && dmax <= 1) continue;  // upper half fully masked
          const int c0 = kk * 32 + lhi * 8;
          bf16x8 se = *(const bf16x8*)&Sx[grow][c0];
          f32x4 gA = *(const f32x4*)&gg[mt * 64 + c0];
          f32x4 gB = *(const f32x4*)&gg[mt * 64 + c0 + 4];
          const int cg0 = p * 64 + c0;
          bf16x8 wfr;
#pragma unroll
          for (int j = 0; j < 4; ++j)
            wfr[j] = (cg0 + j <= grow) ? (__bf16)((float)se[j] * gA[j]) : (__bf16)0.f;
#pragma unroll
          for (int j = 0; j < 4; ++j)
            wfr[4 + j] = (cg0 + 4 + j <= grow) ? (__bf16)((float)se[4 + j] * gB[j]) : (__bf16)0.f;
#pragma unroll
          for (int nh2 = 0; nh2 < 2; ++nh2) oacc[i][nh2] = mfma16(wfr, vf[nh2][kk], oacc[i][nh2]);
        }
      }
    }
    __syncthreads();  // B3: PV readers done before next phase's Sx writes
  }
  // ---- output: this wave's head-half columns of its tile-pair rows ----
#pragma unroll
  for (int i = 0; i < 2; ++i) {
    const int rb = mts[i] * 16 + lhi * 4;
#pragma unroll
    for (int nh2 = 0; nh2 < 2; ++nh2) {
      const int h = (chalf * 2 + nh2) * 16 + l15;
#pragma unroll
      for (int r = 0; r < 4; ++r)
        out[(size_t)b * 16384 + (size_t)(rb + r) * 64 + h] = oacc[i][nh2][r];
    }
  }
}

extern "C" void kernel_launch(void* const* d_in, const int* in_sizes, int n_in,
                              void* d_out, int out_size, void* d_ws, size_t ws_size,
                              hipStream_t stream) {
  const float* x  = (const float*)d_in[0];
  const float* Wq = (const float*)d_in[1];
  const float* Wk = (const float*)d_in[2];
  const float* Wv = (const float*)d_in[3];
  float* out = (float*)d_out;

  unsigned short* kg = (unsigned short*)d_ws;              // [512][256][64] bf16
  unsigned short* vg = kg + (size_t)512 * 256 * 64;        // [512][64][256] bf16
  unsigned short* wf = vg + (size_t)512 * 256 * 64;        // 73728 bf16 frag-packed

  repack_w<<<144, 512, 0, stream>>>(Wq, Wk, Wv, wf);
  fused<<<512, 1024, 0, stream>>>(x, wf, kg, vg, out);
}

// Round 10
// 124.493 us; speedup vs baseline: 2.0716x; 2.0716x over previous
//
#include <hip/hip_runtime.h>

typedef float  f32x4  __attribute__((ext_vector_type(4)));
typedef __bf16 bf16x8 __attribute__((ext_vector_type(8)));

#define CC 384
#define AS1 __attribute__((address_space(1)))
#define AS3 __attribute__((address_space(3)))

__device__ __forceinline__ unsigned short f2bf(float f) {
  union { float f; unsigned int u; } x; x.f = f;
  unsigned int u = x.u;
  return (unsigned short)((u + 0x7fffu + ((u >> 16) & 1u)) >> 16);
}

__device__ __forceinline__ f32x4 mfma16(bf16x8 a, bf16x8 b, f32x4 c) {
  return __builtin_amdgcn_mfma_f32_16x16x32_bf16(a, b, c, 0, 0, 0);
}

// ---------------- kernel 0: repack W into B-fragment layout ----------------
// dst: [ks(0..11)][nt(0..11)][lane(0..63)][j(0..7)] bf16
// element (k, n): ks=k>>5, lane=((k>>3)&3)*16 + (n&15), j=k&7, nt=n>>4
__global__ void repack_w(const float* __restrict__ Wq, const float* __restrict__ Wk,
                         const float* __restrict__ Wv, unsigned short* __restrict__ wf) {
  int e = blockIdx.x * 512 + threadIdx.x;      // 73728 total, exact
  int k = e / 192;
  int n = e - k * 192;
  const float* W = (n < 64) ? Wq : (n < 128) ? Wk : Wv;
  float val = W[k * 64 + (n & 63)];
  int kk = k >> 5;
  int lane = (((k >> 3) & 3) << 4) | (n & 15);
  int j = k & 7;
  int nt = n >> 4;
  wf[(size_t)(((kk * 12 + nt) << 6) + lane) * 8 + j] = f2bf(val);
}

// ---------------- fused kernel: projection + column-softmax attention ----------------
// ONE block per batch, 512 threads / 8 waves.
// Register-budget design (the R5/R9 spill lessons):
//   - projection runs in TWO half-batch passes (rows 0-127 then 128-255), so the
//     accumulator is acc[12] = 48 AGPR (not 96). x still read exactly once.
//   - peak regs ~48 AGPR + ~75 VGPR <= 128 = launch_bounds(512,4) budget -> no spill.
//   - LDS 73,728 B (Sx + stats + dedicated 24.6KB W dbuf; k/v in global like R6)
//     => 2 blocks/CU co-resident, 512 blocks = ONE round; sibling block hides
//     barrier drains (R3-R8: 1 block/CU lockstep left every pipe <20% busy).
// Attention: wave w owns m-tiles {w, 15-w}; R3's proven 2-barrier/phase discipline.
__global__ __launch_bounds__(512, 4) void fused(const float* __restrict__ x,
                                                const unsigned short* __restrict__ wf,
                                                unsigned short* __restrict__ kg,
                                                unsigned short* __restrict__ vg,
                                                float* __restrict__ out) {
  // LDS (73,728 B):
  //  [0, 36864)      Sx[256][72] bf16   (q-scratch, then exp-weights)
  //  [36864, 49152)  pm/ps/gg [16][64] f32
  //  [49152, 73728)  wst: 2 x 6144-short W-stage double buffer (dedicated)
  __shared__ __attribute__((aligned(16))) unsigned char smem[73728];
  unsigned short (*Sx)[72] = (unsigned short(*)[72])smem;
  float* pm = (float*)(smem + 36864);
  float* ps = pm + 1024;
  float* gg = ps + 1024;
  unsigned short* wst = (unsigned short*)(smem + 49152);

  const int tid = threadIdx.x;
  const int w = tid >> 6, lane = tid & 63;
  const int l15 = lane & 15, lhi = lane >> 4;
  const int b = blockIdx.x;
  const int mts[2] = {w, 15 - w};

  f32x4 zero = {0.f, 0.f, 0.f, 0.f};
  const float qs = 0.05103103630798288f;  // 384^-0.5

#define WSTAGE(kp_, b_) do {                                                                  \
    const unsigned short* s_ = wf + (size_t)(kp_) * 6144 + tid * 8;                           \
    unsigned short* d_ = wst + (b_) * 6144 + tid * 8;                                         \
    __builtin_amdgcn_global_load_lds((const AS1 void*)(s_), (AS3 void*)(d_), 16, 0, 0);       \
    if (tid < 256)                                                                            \
      __builtin_amdgcn_global_load_lds((const AS1 void*)(s_ + 4096), (AS3 void*)(d_ + 4096),  \
                                       16, 0, 0);                                             \
  } while (0)

  // ========== projection: 2 half-batches x 12 phases of K=32 ==========
#pragma unroll 1
  for (int hf = 0; hf < 2; ++hf) {
    const float* xr = x + ((size_t)b * 256 + hf * 128 + w * 16 + l15) * CC + lhi * 8;
    f32x4 acc[12];
#pragma unroll
    for (int nt = 0; nt < 12; ++nt) acc[nt] = zero;

    WSTAGE(0, 0);
    f32x4 aC0 = *(const f32x4*)(xr);
    f32x4 aC1 = *(const f32x4*)(xr + 4);

    for (int kp = 0; kp < 12; ++kp) {
      __syncthreads();  // buf[kp&1] staged; prev-buf readers done
      f32x4 aN0 = zero, aN1 = zero;
      if (kp < 11) {
        aN0 = *(const f32x4*)(xr + (kp + 1) * 32);
        aN1 = *(const f32x4*)(xr + (kp + 1) * 32 + 4);
        WSTAGE(kp + 1, (kp + 1) & 1);
      }
      bf16x8 af;
#pragma unroll
      for (int j = 0; j < 4; ++j) { af[j] = (__bf16)aC0[j]; af[4 + j] = (__bf16)aC1[j]; }
      const bf16x8* bp = (const bf16x8*)(wst + (kp & 1) * 6144) + lane;
#pragma unroll
      for (int nt = 0; nt < 12; ++nt) acc[nt] = mfma16(af, bp[nt * 64], acc[nt]);
      aC0 = aN0; aC1 = aN1;
    }
    // half epilogue (own rows / own global cells; no barrier needed).
    // Next half's WSTAGE(0,0) is safe: buf0 last read at kp=10, all waves passed kp=11's
    // top barrier after that.
    const int rbg = hf * 128 + w * 16 + lhi * 4;
#pragma unroll
    for (int nt = 0; nt < 4; ++nt) {
      const int h = nt * 16 + l15;
#pragma unroll
      for (int r = 0; r < 4; ++r) Sx[rbg + r][h] = f2bf(acc[nt][r] * qs);
    }
#pragma unroll
    for (int nt = 4; nt < 8; ++nt) {
      const int h = (nt - 4) * 16 + l15;
#pragma unroll
      for (int r = 0; r < 4; ++r)
        kg[((size_t)b * 256 + rbg + r) * 64 + h] = f2bf(acc[nt][r]);
    }
#pragma unroll
    for (int nt = 8; nt < 12; ++nt) {
      const int h = (nt - 8) * 16 + l15;
      unsigned long long pk =
          (unsigned long long)f2bf(acc[nt][0]) |
          ((unsigned long long)f2bf(acc[nt][1]) << 16) |
          ((unsigned long long)f2bf(acc[nt][2]) << 32) |
          ((unsigned long long)f2bf(acc[nt][3]) << 48);
      *(unsigned long long*)(vg + ((size_t)b * 64 + h) * 256 + rbg) = pk;
    }
  }
#undef WSTAGE
  __syncthreads();  // q complete (cross-wave tiles), k/v global writes drained

  bf16x8 qf[2][2];
#pragma unroll
  for (int i = 0; i < 2; ++i)
#pragma unroll
    for (int kk = 0; kk < 2; ++kk)
      qf[i][kk] = *(const bf16x8*)&Sx[mts[i] * 16 + l15][kk * 32 + lhi * 8];
  // no extra barrier: qf rows and later Sx overwrites of those rows are same-wave

  // ========== attention ==========
  f32x4 oacc[2][4];
#pragma unroll
  for (int i = 0; i < 2; ++i)
#pragma unroll
    for (int nh = 0; nh < 4; ++nh) oacc[i][nh] = zero;

  const size_t kbase = (size_t)b * 256 * 64;
  const size_t vbase = (size_t)b * 64 * 256;

  for (int p = 0; p < 4; ++p) {
    const int p4 = 4 * p;
    const bool any = (mts[1] >= p4);
    // ---- S compute + tile-column stats + exp write (kf loaded per-c: VGPR lean) ----
    if (any) {
#pragma unroll
      for (int c = 0; c < 4; ++c) {
        const bf16x8 kf0 = *(const bf16x8*)(kg + kbase + (size_t)(p * 64 + c * 16 + l15) * 64 + lhi * 8);
        const bf16x8 kf1 = *(const bf16x8*)(kg + kbase + (size_t)(p * 64 + c * 16 + l15) * 64 + 32 + lhi * 8);
        const int cs = c * 16 + l15;
#pragma unroll
        for (int i = 0; i < 2; ++i) {
          const int mt = mts[i];
          if (mt < p4) continue;
          const int cmax = mt - p4;
          const int rowb = mt * 16 + lhi * 4;
          if (c <= cmax) {
            f32x4 s = zero;
            s = mfma16(qf[i][0], kf0, s);
            s = mfma16(qf[i][1], kf1, s);
            const int cg = p * 64 + cs;
            const bool v0 = (rowb + 0) >= cg, v1 = (rowb + 1) >= cg;
            const bool v2 = (rowb + 2) >= cg, v3 = (rowb + 3) >= cg;
            float m = -1e30f;
            m = fmaxf(m, v0 ? s[0] : -1e30f);
            m = fmaxf(m, v1 ? s[1] : -1e30f);
            m = fmaxf(m, v2 ? s[2] : -1e30f);
            m = fmaxf(m, v3 ? s[3] : -1e30f);
            m = fmaxf(m, __shfl_xor(m, 16));
            m = fmaxf(m, __shfl_xor(m, 32));
            const float e0 = v0 ? __expf(s[0] - m) : 0.f;
            const float e1 = v1 ? __expf(s[1] - m) : 0.f;
            const float e2 = v2 ? __expf(s[2] - m) : 0.f;
            const float e3 = v3 ? __expf(s[3] - m) : 0.f;
            float t = e0 + e1 + e2 + e3;
            t += __shfl_xor(t, 16);
            t += __shfl_xor(t, 32);
            Sx[rowb + 0][cs] = f2bf(e0);
            Sx[rowb + 1][cs] = f2bf(e1);
            Sx[rowb + 2][cs] = f2bf(e2);
            Sx[rowb + 3][cs] = f2bf(e3);
            if (lhi == 0) { pm[mt * 64 + cs] = m; ps[mt * 64 + cs] = t; }
          } else {
            if (lhi == 0) { pm[mt * 64 + cs] = -1e30f; ps[mt * 64 + cs] = 0.f; }
          }
        }
      }
    }
    __syncthreads();  // B1: pm/ps/Sx stripe complete
    // ---- per-column reduce (redundant across waves; wave w writes gg rows) ----
    {
      float M = -1e30f;
      for (int mt = p4; mt < 16; ++mt) M = fmaxf(M, pm[mt * 64 + lane]);
      float L = 0.f;
      for (int mt = p4; mt < 16; ++mt) L += ps[mt * 64 + lane] * __expf(pm[mt * 64 + lane] - M);
      const float rv = 1.0f / L;
      int mtw = p4 + w;
      if (mtw < 16) gg[mtw * 64 + lane] = __expf(pm[mtw * 64 + lane] - M) * rv;
      mtw += 8;
      if (mtw < 16) gg[mtw * 64 + lane] = __expf(pm[mtw * 64 + lane] - M) * rv;
    }
    __syncthreads();  // B2: gg ready
    // ---- PV: build wfr pair per kk, stream vf (VGPR lean) ----
    if (any) {
#pragma unroll
      for (int kk = 0; kk < 2; ++kk) {
        bf16x8 wfr2[2];
        bool act[2];
#pragma unroll
        for (int i = 0; i < 2; ++i) {
          const int mt = mts[i];
          act[i] = (mt >= p4) && !(kk == 1 && (mt - p4) <= 1);
          if (act[i]) {
            const int grow = mt * 16 + l15;
            const int c0 = kk * 32 + lhi * 8;
            bf16x8 se = *(const bf16x8*)&Sx[grow][c0];
            f32x4 gA = *(const f32x4*)&gg[mt * 64 + c0];
            f32x4 gB = *(const f32x4*)&gg[mt * 64 + c0 + 4];
            const int cg0 = p * 64 + c0;
            bf16x8 wfr;
#pragma unroll
            for (int j = 0; j < 4; ++j)
              wfr[j] = (cg0 + j <= grow) ? (__bf16)((float)se[j] * gA[j]) : (__bf16)0.f;
#pragma unroll
            for (int j = 0; j < 4; ++j)
              wfr[4 + j] = (cg0 + 4 + j <= grow) ? (__bf16)((float)se[4 + j] * gB[j]) : (__bf16)0.f;
            wfr2[i] = wfr;
          }
        }
        if (!act[0] && !act[1]) continue;
#pragma unroll
        for (int nh = 0; nh < 4; ++nh) {
          const bf16x8 vf = *(const bf16x8*)(vg + vbase + (size_t)(nh * 16 + l15) * 256 + p * 64 + kk * 32 + lhi * 8);
          if (act[0]) oacc[0][nh] = mfma16(wfr2[0], vf, oacc[0][nh]);
          if (act[1]) oacc[1][nh] = mfma16(wfr2[1], vf, oacc[1][nh]);
        }
      }
    }
    // no B3: next phase's Sx writes are same-wave rows as this phase's PV reads
  }
  // ---- output ----
#pragma unroll
  for (int i = 0; i < 2; ++i) {
    const int rb = mts[i] * 16 + lhi * 4;
#pragma unroll
    for (int nh = 0; nh < 4; ++nh) {
      const int h = nh * 16 + l15;
#pragma unroll
      for (int r = 0; r < 4; ++r)
        out[(size_t)b * 16384 + (size_t)(rb + r) * 64 + h] = oacc[i][nh][r];
    }
  }
}

extern "C" void kernel_launch(void* const* d_in, const int* in_sizes, int n_in,
                              void* d_out, int out_size, void* d_ws, size_t ws_size,
                              hipStream_t stream) {
  const float* x  = (const float*)d_in[0];
  const float* Wq = (const float*)d_in[1];
  const float* Wk = (const float*)d_in[2];
  const float* Wv = (const float*)d_in[3];
  float* out = (float*)d_out;

  unsigned short* kg = (unsigned short*)d_ws;              // [512][256][64] bf16
  unsigned short* vg = kg + (size_t)512 * 256 * 64;        // [512][64][256] bf16
  unsigned short* wf = vg + (size_t)512 * 256 * 64;        // 73728 bf16 frag-packed

  repack_w<<<144, 512, 0, stream>>>(Wq, Wk, Wv, wf);
  fused<<<512, 512, 0, stream>>>(x, wf, kg, vg, out);
}

// Round 11
// 85.415 us; speedup vs baseline: 3.0193x; 1.4575x over previous
//
#include <hip/hip_runtime.h>

typedef float  f32x4  __attribute__((ext_vector_type(4)));
typedef __bf16 bf16x8 __attribute__((ext_vector_type(8)));

#define CC 384
#define AS1 __attribute__((address_space(1)))
#define AS3 __attribute__((address_space(3)))

__device__ __forceinline__ unsigned short f2bf(float f) {
  union { float f; unsigned int u; } x; x.f = f;
  unsigned int u = x.u;
  return (unsigned short)((u + 0x7fffu + ((u >> 16) & 1u)) >> 16);
}

__device__ __forceinline__ f32x4 mfma16(bf16x8 a, bf16x8 b, f32x4 c) {
  return __builtin_amdgcn_mfma_f32_16x16x32_bf16(a, b, c, 0, 0, 0);
}

// ---------------- kernel 0: repack W into B-fragment layout ----------------
// dst: [ks(0..11)][nt(0..11)][lane(0..63)][j(0..7)] bf16
// element (k, n): ks=k>>5, lane=((k>>3)&3)*16 + (n&15), j=k&7, nt=n>>4
__global__ void repack_w(const float* __restrict__ Wq, const float* __restrict__ Wk,
                         const float* __restrict__ Wv, unsigned short* __restrict__ wf) {
  int e = blockIdx.x * 512 + threadIdx.x;      // 73728 total, exact
  int k = e / 192;
  int n = e - k * 192;
  const float* W = (n < 64) ? Wq : (n < 128) ? Wk : Wv;
  float val = W[k * 64 + (n & 63)];
  int kk = k >> 5;
  int lane = (((k >> 3) & 3) << 4) | (n & 15);
  int j = k & 7;
  int nt = n >> 4;
  wf[(size_t)(((kk * 12 + nt) << 6) + lane) * 8 + j] = f2bf(val);
}

// ---------------- fused kernel: projection + stripe-overlapped column-softmax attention --
// ONE block per batch, 512 threads / 8 waves; wave w owns m-tiles {w, 15-w}.
// Ten-round lesson (R3-R10 measured): occupancy levers all regress —
//   2 blocks/CU via LDS diet + global k/v (R6,R10): k/v round-trip + write amp, slower;
//   VGPR caps (R5,R9): acc spills, catastrophic; 16-wave (R8): more lockstep barriers;
//   counted-vmcnt asm (R7): sched pins beat the win. Best = all-LDS 1-block/CU (R3).
// The kernel is bound by the SERIAL CHAIN of thin barrier regions, so R11 keeps the
// R3 chassis and fattens each region: Sx double-buffer lets PV(stripe p) co-schedule
// with S(stripe p+1) in ONE region (same barrier count, ~2x work per region).
__global__ __launch_bounds__(512, 2) void fused(const float* __restrict__ x,
                                                const unsigned short* __restrict__ wf,
                                                float* __restrict__ out) {
  // LDS layout (156,672 B <= 160 KiB):
  //  [0, 36864)        Sx0[256][72] bf16   (q-scratch / exp stripe even; W-stage overlay)
  //  [36864, 73728)    Sx1[256][72] bf16   (exp stripe odd)
  //  [73728, 110592)   kL[256][72] bf16
  //  [110592, 144384)  vT[64][264] bf16
  //  [144384, 156672)  pm/ps/gg [16][64] f32 each
  __shared__ __attribute__((aligned(16))) unsigned char smem[156672];
  __bf16 (*Sx0)[72] = (__bf16(*)[72])smem;
  __bf16 (*Sx1)[72] = (__bf16(*)[72])(smem + 36864);
  unsigned short (*kL)[72] = (unsigned short(*)[72])(smem + 73728);
  unsigned short (*vT)[264] = (unsigned short(*)[264])(smem + 110592);
  float* pm = (float*)(smem + 144384);
  float* ps = pm + 1024;
  float* gg = ps + 1024;
  unsigned short* wst = (unsigned short*)smem;   // W stage: 2 x 6144 shorts (overlays Sx0)

  const int tid = threadIdx.x;
  const int w = tid >> 6, lane = tid & 63;
  const int l15 = lane & 15, lhi = lane >> 4;
  const int b = blockIdx.x;
  const int mts[2] = {w, 15 - w};

  // ================= projection (byte-identical structure to R3, 82.9us) =================
  const float* xr0 = x + ((size_t)b * 256 + mts[0] * 16 + l15) * CC + lhi * 8;
  const float* xr1 = x + ((size_t)b * 256 + mts[1] * 16 + l15) * CC + lhi * 8;

  f32x4 zero = {0.f, 0.f, 0.f, 0.f};
  f32x4 acc[2][12];
#pragma unroll
  for (int i = 0; i < 2; ++i)
#pragma unroll
    for (int nt = 0; nt < 12; ++nt) acc[i][nt] = zero;

#define STAGE(kp_, b_) do {                                                                   \
    const unsigned short* s_ = wf + (size_t)(kp_) * 6144 + tid * 8;                           \
    unsigned short* d_ = wst + (b_) * 6144 + tid * 8;                                         \
    __builtin_amdgcn_global_load_lds((const AS1 void*)(s_), (AS3 void*)(d_), 16, 0, 0);       \
    if (tid < 256)                                                                            \
      __builtin_amdgcn_global_load_lds((const AS1 void*)(s_ + 4096), (AS3 void*)(d_ + 4096),  \
                                       16, 0, 0);                                             \
  } while (0)

  STAGE(0, 0);
  f32x4 aC[2][2];
  aC[0][0] = *(const f32x4*)(xr0);     aC[0][1] = *(const f32x4*)(xr0 + 4);
  aC[1][0] = *(const f32x4*)(xr1);     aC[1][1] = *(const f32x4*)(xr1 + 4);

  for (int kp = 0; kp < 12; ++kp) {
    __syncthreads();  // buf[kp&1] staged; prev-buf readers done
    f32x4 aN[2][2];
#pragma unroll
    for (int i = 0; i < 2; ++i) { aN[i][0] = zero; aN[i][1] = zero; }
    if (kp < 11) {
      const int o = (kp + 1) * 32;
      aN[0][0] = *(const f32x4*)(xr0 + o);     aN[0][1] = *(const f32x4*)(xr0 + o + 4);
      aN[1][0] = *(const f32x4*)(xr1 + o);     aN[1][1] = *(const f32x4*)(xr1 + o + 4);
      STAGE(kp + 1, (kp + 1) & 1);
    }
    const bf16x8* bp = (const bf16x8*)(wst + (kp & 1) * 6144) + lane;
#pragma unroll
    for (int i = 0; i < 2; ++i) {
      bf16x8 af;
#pragma unroll
      for (int j = 0; j < 4; ++j) { af[j] = (__bf16)aC[i][0][j]; af[4 + j] = (__bf16)aC[i][1][j]; }
#pragma unroll
      for (int nt = 0; nt < 12; ++nt) acc[i][nt] = mfma16(af, bp[nt * 64], acc[i][nt]);
    }
#pragma unroll
    for (int i = 0; i < 2; ++i) { aC[i][0] = aN[i][0]; aC[i][1] = aN[i][1]; }
  }
#undef STAGE
  __syncthreads();  // all W-stage reads done; Sx0 region free for q-scratch

  // epilogue: q (scaled) -> Sx0 scratch, k -> kL, v -> vT (transposed, packed b64)
  const float qs = 0.05103103630798288f;  // 384^-0.5
#pragma unroll
  for (int i = 0; i < 2; ++i) {
    const int rb = mts[i] * 16 + lhi * 4;
#pragma unroll
    for (int nt = 0; nt < 4; ++nt) {
      const int h = nt * 16 + l15;
#pragma unroll
      for (int r = 0; r < 4; ++r)
        *(unsigned short*)&Sx0[rb + r][h] = f2bf(acc[i][nt][r] * qs);
    }
#pragma unroll
    for (int nt = 4; nt < 8; ++nt) {
      const int h = (nt - 4) * 16 + l15;
#pragma unroll
      for (int r = 0; r < 4; ++r) kL[rb + r][h] = f2bf(acc[i][nt][r]);
    }
#pragma unroll
    for (int nt = 8; nt < 12; ++nt) {
      const int h = (nt - 8) * 16 + l15;
      unsigned long long pk =
          (unsigned long long)f2bf(acc[i][nt][0]) |
          ((unsigned long long)f2bf(acc[i][nt][1]) << 16) |
          ((unsigned long long)f2bf(acc[i][nt][2]) << 32) |
          ((unsigned long long)f2bf(acc[i][nt][3]) << 48);
      *(unsigned long long*)&vT[h][rb] = pk;
    }
  }
  __syncthreads();  // q/k/v LDS-resident

  bf16x8 qf[2][2];
#pragma unroll
  for (int i = 0; i < 2; ++i)
#pragma unroll
    for (int kk = 0; kk < 2; ++kk)
      qf[i][kk] = *(const bf16x8*)&Sx0[mts[i] * 16 + l15][kk * 32 + lhi * 8];
  // qf rows are wave-private; S(0)'s overwrite of them is same-wave program order

  // ================= attention: stripe-overlapped =================
  f32x4 oacc[2][4];
#pragma unroll
  for (int i = 0; i < 2; ++i)
#pragma unroll
    for (int nh = 0; nh < 4; ++nh) oacc[i][nh] = zero;

  // S-compute for stripe sp into SxW: QK^T, tile-column max/sumexp, exp write
  auto do_S = [&](int sp, __bf16 (*SxW)[72]) {
    const int p4 = 4 * sp;
    if (mts[1] < p4) return;
    bf16x8 kf[4][2];
#pragma unroll
    for (int c = 0; c < 4; ++c)
#pragma unroll
      for (int kk = 0; kk < 2; ++kk)
        kf[c][kk] = *(const bf16x8*)&kL[sp * 64 + c * 16 + l15][kk * 32 + lhi * 8];
#pragma unroll
    for (int i = 0; i < 2; ++i) {
      const int mt = mts[i];
      if (mt < p4) continue;
      const int cmax = mt - p4;
      const int rowb = mt * 16 + lhi * 4;
#pragma unroll
      for (int c = 0; c < 4; ++c) {
        const int cs = c * 16 + l15;
        if (c <= cmax) {
          f32x4 s = zero;
          s = mfma16(qf[i][0], kf[c][0], s);
          s = mfma16(qf[i][1], kf[c][1], s);
          const int cg = sp * 64 + cs;
          const bool v0 = (rowb + 0) >= cg, v1 = (rowb + 1) >= cg;
          const bool v2 = (rowb + 2) >= cg, v3 = (rowb + 3) >= cg;
          float m = -1e30f;
          m = fmaxf(m, v0 ? s[0] : -1e30f);
          m = fmaxf(m, v1 ? s[1] : -1e30f);
          m = fmaxf(m, v2 ? s[2] : -1e30f);
          m = fmaxf(m, v3 ? s[3] : -1e30f);
          m = fmaxf(m, __shfl_xor(m, 16));
          m = fmaxf(m, __shfl_xor(m, 32));
          const float e0 = v0 ? __expf(s[0] - m) : 0.f;
          const float e1 = v1 ? __expf(s[1] - m) : 0.f;
          const float e2 = v2 ? __expf(s[2] - m) : 0.f;
          const float e3 = v3 ? __expf(s[3] - m) : 0.f;
          float t = e0 + e1 + e2 + e3;
          t += __shfl_xor(t, 16);
          t += __shfl_xor(t, 32);
          SxW[rowb + 0][cs] = (__bf16)e0;
          SxW[rowb + 1][cs] = (__bf16)e1;
          SxW[rowb + 2][cs] = (__bf16)e2;
          SxW[rowb + 3][cs] = (__bf16)e3;
          if (lhi == 0) { pm[mt * 64 + cs] = m; ps[mt * 64 + cs] = t; }
        } else {
          if (lhi == 0) { pm[mt * 64 + cs] = -1e30f; ps[mt * 64 + cs] = 0.f; }
        }
      }
    }
  };

  // PV for stripe sp from SxR
  auto do_PV = [&](int sp, const __bf16 (*SxR)[72]) {
    const int p4 = 4 * sp;
    if (mts[1] < p4) return;
    bf16x8 vf[4][2];
#pragma unroll
    for (int nh = 0; nh < 4; ++nh)
#pragma unroll
      for (int kk = 0; kk < 2; ++kk)
        vf[nh][kk] = *(const bf16x8*)&vT[nh * 16 + l15][sp * 64 + kk * 32 + lhi * 8];
#pragma unroll
    for (int i = 0; i < 2; ++i) {
      const int mt = mts[i];
      if (mt < p4) continue;
      const int grow = mt * 16 + l15;
      const int dmax = mt - p4;
#pragma unroll
      for (int kk = 0; kk < 2; ++kk) {
        if (kk == 1 && dmax <= 1) continue;  // upper half fully masked
        const int c0 = kk * 32 + lhi * 8;
        bf16x8 se = *(const bf16x8*)&SxR[grow][c0];
        f32x4 gA = *(const f32x4*)&gg[mt * 64 + c0];
        f32x4 gB = *(const f32x4*)&gg[mt * 64 + c0 + 4];
        const int cg0 = sp * 64 + c0;
        bf16x8 wfr;
#pragma unroll
        for (int j = 0; j < 4; ++j)
          wfr[j] = (cg0 + j <= grow) ? (__bf16)((float)se[j] * gA[j]) : (__bf16)0.f;
#pragma unroll
        for (int j = 0; j < 4; ++j)
          wfr[4 + j] = (cg0 + 4 + j <= grow) ? (__bf16)((float)se[4 + j] * gB[j]) : (__bf16)0.f;
#pragma unroll
        for (int nh = 0; nh < 4; ++nh) oacc[i][nh] = mfma16(wfr, vf[nh][kk], oacc[i][nh]);
      }
    }
  };

  do_S(0, Sx0);
  __syncthreads();  // B1(0): stripe-0 pm/ps/Sx complete
  for (int p = 0; p < 4; ++p) {
    const int p4 = 4 * p;
    // ---- per-column reduce (redundant across waves; wave w writes its gg rows) ----
    {
      float M = -1e30f;
      for (int mt = p4; mt < 16; ++mt) M = fmaxf(M, pm[mt * 64 + lane]);
      float L = 0.f;
      for (int mt = p4; mt < 16; ++mt) L += ps[mt * 64 + lane] * __expf(pm[mt * 64 + lane] - M);
      const float rv = 1.0f / L;
      int mtw = p4 + w;
      if (mtw < 16) gg[mtw * 64 + lane] = __expf(pm[mtw * 64 + lane] - M) * rv;
      mtw += 8;
      if (mtw < 16) gg[mtw * 64 + lane] = __expf(pm[mtw * 64 + lane] - M) * rv;
    }
    __syncthreads();  // B2(p): gg ready; pm/ps readers done (S(p+1) may overwrite after)
    // ---- fat region: PV(p) co-scheduled with S(p+1) ----
    do_PV(p, (p & 1) ? (const __bf16(*)[72])Sx1 : (const __bf16(*)[72])Sx0);
    if (p < 3) {
      do_S(p + 1, (p & 1) ? Sx0 : Sx1);
      __syncthreads();  // B1(p+1): stripe p+1 pm/ps/Sx complete
    }
  }
  // ---- output ----
#pragma unroll
  for (int i = 0; i < 2; ++i) {
    const int rb = mts[i] * 16 + lhi * 4;
#pragma unroll
    for (int nh = 0; nh < 4; ++nh) {
      const int h = nh * 16 + l15;
#pragma unroll
      for (int r = 0; r < 4; ++r)
        out[(size_t)b * 16384 + (size_t)(rb + r) * 64 + h] = oacc[i][nh][r];
    }
  }
}

extern "C" void kernel_launch(void* const* d_in, const int* in_sizes, int n_in,
                              void* d_out, int out_size, void* d_ws, size_t ws_size,
                              hipStream_t stream) {
  const float* x  = (const float*)d_in[0];
  const float* Wq = (const float*)d_in[1];
  const float* Wk = (const float*)d_in[2];
  const float* Wv = (const float*)d_in[3];
  float* out = (float*)d_out;

  unsigned short* wf = (unsigned short*)d_ws;   // 73728 bf16 frag-packed W

  repack_w<<<144, 512, 0, stream>>>(Wq, Wk, Wv, wf);
  fused<<<512, 512, 0, stream>>>(x, wf, out);
}